// Round 1
// baseline (2446.789 us; speedup 1.0000x reference)
//
#include <hip/hip_runtime.h>

#define NU 100000
#define NS 50000
#define NG 50
#define NW 20000
#define NT 10
#define CDIM 64
#define FDIM 384
#define CNT_TOTAL (4 * NS + NU + NG + NW + NT)  // 320060

// ---------------------------------------------------------------------------
// Segmented GEMM: out[m,c] = relu?( sum_seg sum_k Ahat[m,k] * W[c,k] + bias )
// where Ahat = A / max(cnt,1) when cnt != nullptr (fused mean).
// Tile: 64 (M) x 64 (N=C) per block, 256 threads, 4x4 micro-tile per thread.
// LDS tiles stored K-major with stride 68 (aligned float4 reads, ~2-way max
// bank conflicts on both read and write paths).
// ---------------------------------------------------------------------------
struct GemmSeg { const float* A; const float* W; const int* cnt; int F; };
struct GemmArgs {
  GemmSeg seg[8];
  const float* bias[4];
  float* out;
  int nseg, nbias, M, relu;
};

__global__ __launch_bounds__(256) void seg_gemm(GemmArgs args) {
  __shared__ __align__(16) float As[64][68];
  __shared__ __align__(16) float Bs[64][68];
  const int tid = threadIdx.x;
  const int tc = tid & 15;   // col group (fastest -> coalesced C stores)
  const int tm = tid >> 4;   // row group
  const int m0 = blockIdx.x * 64;
  const int lm = tid >> 4;        // loader row 0..15 (+16*i)
  const int lk = (tid & 15) * 4;  // loader k offset (float4)

  float acc[4][4] = {};

  for (int s = 0; s < args.nseg; ++s) {
    const float* __restrict__ A = args.seg[s].A;
    const float* __restrict__ W = args.seg[s].W;
    const int* __restrict__ cnt = args.seg[s].cnt;
    const int F = args.seg[s].F;
    for (int k0 = 0; k0 < F; k0 += 64) {
      // A tile (rows = nodes, transposed into K-major LDS)
#pragma unroll
      for (int i = 0; i < 4; ++i) {
        int m = i * 16 + lm;
        int gm = m0 + m;
        float4 v = make_float4(0.f, 0.f, 0.f, 0.f);
        if (gm < args.M) {
          v = *(const float4*)(A + (size_t)gm * F + k0 + lk);
          if (cnt) {
            float sc = 1.0f / fmaxf((float)cnt[gm], 1.0f);
            v.x *= sc; v.y *= sc; v.z *= sc; v.w *= sc;
          }
        }
        As[lk + 0][m] = v.x; As[lk + 1][m] = v.y;
        As[lk + 2][m] = v.z; As[lk + 3][m] = v.w;
      }
      // W tile: W is [64][F] row-major
#pragma unroll
      for (int i = 0; i < 4; ++i) {
        int c = i * 16 + lm;
        float4 v = *(const float4*)(W + (size_t)c * F + k0 + lk);
        Bs[lk + 0][c] = v.x; Bs[lk + 1][c] = v.y;
        Bs[lk + 2][c] = v.z; Bs[lk + 3][c] = v.w;
      }
      __syncthreads();
#pragma unroll 8
      for (int k = 0; k < 64; ++k) {
        float4 a = *(const float4*)&As[k][tm * 4];
        float4 w = *(const float4*)&Bs[k][tc * 4];
        acc[0][0] += a.x * w.x; acc[0][1] += a.x * w.y; acc[0][2] += a.x * w.z; acc[0][3] += a.x * w.w;
        acc[1][0] += a.y * w.x; acc[1][1] += a.y * w.y; acc[1][2] += a.y * w.z; acc[1][3] += a.y * w.w;
        acc[2][0] += a.z * w.x; acc[2][1] += a.z * w.y; acc[2][2] += a.z * w.z; acc[2][3] += a.z * w.w;
        acc[3][0] += a.w * w.x; acc[3][1] += a.w * w.y; acc[3][2] += a.w * w.z; acc[3][3] += a.w * w.w;
      }
      __syncthreads();
    }
  }

  float b[4] = {0.f, 0.f, 0.f, 0.f};
  for (int i = 0; i < args.nbias; ++i) {
    const float* bp = args.bias[i];
#pragma unroll
    for (int j = 0; j < 4; ++j) b[j] += bp[tc * 4 + j];
  }
#pragma unroll
  for (int i = 0; i < 4; ++i) {
    int gm = m0 + tm * 4 + i;
    if (gm < args.M) {
      float4 o;
      o.x = acc[i][0] + b[0];
      o.y = acc[i][1] + b[1];
      o.z = acc[i][2] + b[2];
      o.w = acc[i][3] + b[3];
      if (args.relu) {
        o.x = fmaxf(o.x, 0.f); o.y = fmaxf(o.y, 0.f);
        o.z = fmaxf(o.z, 0.f); o.w = fmaxf(o.w, 0.f);
      }
      *(float4*)(args.out + (size_t)gm * CDIM + tc * 4) = o;
    }
  }
}

// ---------------------------------------------------------------------------
// Degree count: one atomic per edge.
// ---------------------------------------------------------------------------
__global__ __launch_bounds__(256) void count_k(const int* __restrict__ dst, int E,
                                               int* __restrict__ cnt) {
  int i = blockIdx.x * 256 + threadIdx.x;
  if (i < E) atomicAdd(&cnt[dst[i]], 1);
}

// ---------------------------------------------------------------------------
// Scatter-add of 64-float rows: one wave per edge (lane = channel).
// Coalesced 256B gather, 64 coalesced fp32 atomics per edge.
// ---------------------------------------------------------------------------
__global__ __launch_bounds__(256) void scatter_k(const int* __restrict__ src,
                                                 const int* __restrict__ dst, int E,
                                                 const float* __restrict__ x,
                                                 float* __restrict__ agg) {
  long long gid = (long long)blockIdx.x * 256 + threadIdx.x;
  int e = (int)(gid >> 6);
  int c = (int)(gid & 63);
  if (e < E) {
    int s = src[e];
    int d = dst[e];
    atomicAdd(&agg[(size_t)d * CDIM + c], x[(size_t)s * CDIM + c]);
  }
}

// ---------------------------------------------------------------------------
// Edge scoring: one wave per edge, wave-reduce dot over 64 channels.
// ---------------------------------------------------------------------------
__global__ __launch_bounds__(256) void score_k(const int* __restrict__ eli, int E,
                                               const float* __restrict__ xu,
                                               const float* __restrict__ xs,
                                               float* __restrict__ out) {
  long long gid = (long long)blockIdx.x * 256 + threadIdx.x;
  int e = (int)(gid >> 6);
  int c = (int)(gid & 63);
  if (e < E) {
    int u = eli[e];
    int sv = eli[E + e];
    float p = xu[(size_t)u * CDIM + c] * xs[(size_t)sv * CDIM + c];
#pragma unroll
    for (int off = 32; off > 0; off >>= 1) p += __shfl_down(p, off, 64);
    if (c == 0) out[e] = p;
  }
}

extern "C" void kernel_launch(void* const* d_in, const int* in_sizes, int n_in,
                              void* d_out, int out_size, void* d_ws, size_t ws_size,
                              hipStream_t stream) {
  const float* reviews  = (const float*)d_in[0];
  const float* overview = (const float*)d_in[1];
  const float* g_emb    = (const float*)d_in[2];
  const float* w_emb    = (const float*)d_in[3];
  const float* t_emb    = (const float*)d_in[4];
  const float* Wu  = (const float*)d_in[5];
  const float* bu  = (const float*)d_in[6];
  const float* Wsp = (const float*)d_in[7];
  const float* bs  = (const float*)d_in[8];
  const float* Wl1 = (const float*)d_in[9];
  const float* bl1 = (const float*)d_in[10];
  const float* Wr1 = (const float*)d_in[11];
  const float* Wl2 = (const float*)d_in[12];
  const float* bl2 = (const float*)d_in[13];
  const float* Wr2 = (const float*)d_in[14];
  const int* e_u2s = (const int*)d_in[15];
  const int* e_g2s = (const int*)d_in[16];
  const int* e_w2s = (const int*)d_in[17];
  const int* e_t2s = (const int*)d_in[18];
  const int* eli   = (const int*)d_in[19];
  const int E_u = in_sizes[15] / 2;
  const int E_g = in_sizes[16] / 2;
  const int E_w = in_sizes[17] / 2;
  const int E_t = in_sizes[18] / 2;
  const int E_l = in_sizes[19] / 2;

  // ---- workspace layout (floats) ----
  float* ws = (float*)d_ws;
  size_t off = 0;
  auto take = [&](size_t n) { float* p = ws + off; off += n; return p; };
  float* x0u = take((size_t)NU * CDIM);
  float* x0s = take((size_t)NS * CDIM);
  float* x1u = take((size_t)NU * CDIM);
  float* x1s = take((size_t)NS * CDIM);
  float* x1g = take((size_t)NG * CDIM);
  float* x1w = take((size_t)NW * CDIM);
  float* x1t = take((size_t)NT * CDIM);
  float* aggbase = ws + off;
  float* agg0 = take((size_t)NS * CDIM);
  float* agg1 = take((size_t)NU * CDIM);
  float* agg2 = take((size_t)NS * CDIM);
  float* agg3 = take((size_t)NG * CDIM);
  float* agg4 = take((size_t)NS * CDIM);
  float* agg5 = take((size_t)NW * CDIM);
  float* agg6 = take((size_t)NS * CDIM);
  float* agg7 = take((size_t)NT * CDIM);
  size_t aggfloats = (size_t)((ws + off) - aggbase);
  int* cnti = (int*)take((size_t)CNT_TOTAL);
  int* cnt0 = cnti;
  int* cnt1 = cnt0 + NS;
  int* cnt2 = cnt1 + NU;
  int* cnt3 = cnt2 + NS;
  int* cnt4 = cnt3 + NG;
  int* cnt5 = cnt4 + NS;
  int* cnt6 = cnt5 + NW;
  int* cnt7 = cnt6 + NS;
  // x2 aliases x0 (dead after layer-1 GEMMs)
  float* x2u = x0u;
  float* x2s = x0s;

  struct ET { const int* src; const int* dst; int E; };
  ET et[8] = {
      {e_u2s,       e_u2s + E_u, E_u},  // 0 users->series
      {e_u2s + E_u, e_u2s,       E_u},  // 1 series->users
      {e_g2s,       e_g2s + E_g, E_g},  // 2 genres->series
      {e_g2s + E_g, e_g2s,       E_g},  // 3 series->genres
      {e_w2s,       e_w2s + E_w, E_w},  // 4 writer->series
      {e_w2s + E_w, e_w2s,       E_w},  // 5 series->writer
      {e_t2s,       e_t2s + E_t, E_t},  // 6 type->series
      {e_t2s + E_t, e_t2s,       E_t},  // 7 series->type
  };
  float* agg[8] = {agg0, agg1, agg2, agg3, agg4, agg5, agg6, agg7};
  int*   cnt[8] = {cnt0, cnt1, cnt2, cnt3, cnt4, cnt5, cnt6, cnt7};

  // ---- projections ----
  {
    GemmArgs a{};
    a.seg[0] = {reviews, Wu, nullptr, FDIM}; a.nseg = 1;
    a.bias[0] = bu; a.nbias = 1;
    a.out = x0u; a.M = NU; a.relu = 0;
    seg_gemm<<<(NU + 63) / 64, 256, 0, stream>>>(a);
  }
  {
    GemmArgs a{};
    a.seg[0] = {overview, Wsp, nullptr, FDIM}; a.nseg = 1;
    a.bias[0] = bs; a.nbias = 1;
    a.out = x0s; a.M = NS; a.relu = 0;
    seg_gemm<<<(NS + 63) / 64, 256, 0, stream>>>(a);
  }

  // ---- zero aggs + counts, build counts (shared by both layers) ----
  hipMemsetAsync(aggbase, 0, (aggfloats + CNT_TOTAL) * sizeof(float), stream);
  for (int i = 0; i < 8; ++i)
    count_k<<<(et[i].E + 255) / 256, 256, 0, stream>>>(et[i].dst, et[i].E, cnt[i]);

  // ---- layer 1 scatter ----
  const float* xsrc1[8] = {x0u, x0s, g_emb, x0s, w_emb, x0s, t_emb, x0s};
  for (int i = 0; i < 8; ++i) {
    long long thr = (long long)et[i].E * 64;
    scatter_k<<<(unsigned)((thr + 255) / 256), 256, 0, stream>>>(
        et[i].src, et[i].dst, et[i].E, xsrc1[i], agg[i]);
  }

  // ---- layer 1 output GEMMs (+ReLU) ----
  {  // series
    GemmArgs a{};
    a.seg[0] = {agg0, Wl1 + 0 * 4096, cnt0, 64};
    a.seg[1] = {agg2, Wl1 + 2 * 4096, cnt2, 64};
    a.seg[2] = {agg4, Wl1 + 4 * 4096, cnt4, 64};
    a.seg[3] = {agg6, Wl1 + 6 * 4096, cnt6, 64};
    a.seg[4] = {x0s, Wr1 + 0 * 4096, nullptr, 64};
    a.seg[5] = {x0s, Wr1 + 2 * 4096, nullptr, 64};
    a.seg[6] = {x0s, Wr1 + 4 * 4096, nullptr, 64};
    a.seg[7] = {x0s, Wr1 + 6 * 4096, nullptr, 64};
    a.nseg = 8;
    a.bias[0] = bl1 + 0 * 64; a.bias[1] = bl1 + 2 * 64;
    a.bias[2] = bl1 + 4 * 64; a.bias[3] = bl1 + 6 * 64; a.nbias = 4;
    a.out = x1s; a.M = NS; a.relu = 1;
    seg_gemm<<<(NS + 63) / 64, 256, 0, stream>>>(a);
  }
  {  // users
    GemmArgs a{};
    a.seg[0] = {agg1, Wl1 + 1 * 4096, cnt1, 64};
    a.seg[1] = {x0u, Wr1 + 1 * 4096, nullptr, 64};
    a.nseg = 2;
    a.bias[0] = bl1 + 1 * 64; a.nbias = 1;
    a.out = x1u; a.M = NU; a.relu = 1;
    seg_gemm<<<(NU + 63) / 64, 256, 0, stream>>>(a);
  }
  {  // genres
    GemmArgs a{};
    a.seg[0] = {agg3, Wl1 + 3 * 4096, cnt3, 64};
    a.seg[1] = {g_emb, Wr1 + 3 * 4096, nullptr, 64};
    a.nseg = 2;
    a.bias[0] = bl1 + 3 * 64; a.nbias = 1;
    a.out = x1g; a.M = NG; a.relu = 1;
    seg_gemm<<<(NG + 63) / 64, 256, 0, stream>>>(a);
  }
  {  // writer
    GemmArgs a{};
    a.seg[0] = {agg5, Wl1 + 5 * 4096, cnt5, 64};
    a.seg[1] = {w_emb, Wr1 + 5 * 4096, nullptr, 64};
    a.nseg = 2;
    a.bias[0] = bl1 + 5 * 64; a.nbias = 1;
    a.out = x1w; a.M = NW; a.relu = 1;
    seg_gemm<<<(NW + 63) / 64, 256, 0, stream>>>(a);
  }
  {  // type
    GemmArgs a{};
    a.seg[0] = {agg7, Wl1 + 7 * 4096, cnt7, 64};
    a.seg[1] = {t_emb, Wr1 + 7 * 4096, nullptr, 64};
    a.nseg = 2;
    a.bias[0] = bl1 + 7 * 64; a.nbias = 1;
    a.out = x1t; a.M = NT; a.relu = 1;
    seg_gemm<<<(NT + 63) / 64, 256, 0, stream>>>(a);
  }

  // ---- layer 2 scatter (only dst types users/series needed) ----
  hipMemsetAsync(aggbase, 0, aggfloats * sizeof(float), stream);  // counts preserved
  const float* xsrc2[8] = {x1u, x1s, x1g, nullptr, x1w, nullptr, x1t, nullptr};
  const int l2types[5] = {0, 1, 2, 4, 6};
  for (int j = 0; j < 5; ++j) {
    int i = l2types[j];
    long long thr = (long long)et[i].E * 64;
    scatter_k<<<(unsigned)((thr + 255) / 256), 256, 0, stream>>>(
        et[i].src, et[i].dst, et[i].E, xsrc2[i], agg[i]);
  }

  // ---- layer 2 output GEMMs (no ReLU) ----
  {  // series -> x2s (aliases x0s; reads x1s/aggs only)
    GemmArgs a{};
    a.seg[0] = {agg0, Wl2 + 0 * 4096, cnt0, 64};
    a.seg[1] = {agg2, Wl2 + 2 * 4096, cnt2, 64};
    a.seg[2] = {agg4, Wl2 + 4 * 4096, cnt4, 64};
    a.seg[3] = {agg6, Wl2 + 6 * 4096, cnt6, 64};
    a.seg[4] = {x1s, Wr2 + 0 * 4096, nullptr, 64};
    a.seg[5] = {x1s, Wr2 + 2 * 4096, nullptr, 64};
    a.seg[6] = {x1s, Wr2 + 4 * 4096, nullptr, 64};
    a.seg[7] = {x1s, Wr2 + 6 * 4096, nullptr, 64};
    a.nseg = 8;
    a.bias[0] = bl2 + 0 * 64; a.bias[1] = bl2 + 2 * 64;
    a.bias[2] = bl2 + 4 * 64; a.bias[3] = bl2 + 6 * 64; a.nbias = 4;
    a.out = x2s; a.M = NS; a.relu = 0;
    seg_gemm<<<(NS + 63) / 64, 256, 0, stream>>>(a);
  }
  {  // users -> x2u
    GemmArgs a{};
    a.seg[0] = {agg1, Wl2 + 1 * 4096, cnt1, 64};
    a.seg[1] = {x1u, Wr2 + 1 * 4096, nullptr, 64};
    a.nseg = 2;
    a.bias[0] = bl2 + 1 * 64; a.nbias = 1;
    a.out = x2u; a.M = NU; a.relu = 0;
    seg_gemm<<<(NU + 63) / 64, 256, 0, stream>>>(a);
  }

  // ---- scoring ----
  {
    long long thr = (long long)E_l * 64;
    score_k<<<(unsigned)((thr + 255) / 256), 256, 0, stream>>>(
        eli, E_l, x2u, x2s, (float*)d_out);
  }
}